// Round 6
// baseline (1279.917 us; speedup 1.0000x reference)
//
#include <hip/hip_runtime.h>
#include <type_traits>

#define DIMC 512
#define NTOK 4097
#define GH 64
#define GW 64
#define TH 8    // output rows per thread (7-slot accumulator ring)
#define WT 4    // output cols per thread

// Compile-time-for: every array index is a template constant -> SROA promotes.
template <int I, int N, typename F>
__device__ __forceinline__ void static_for(F&& f)
{
    if constexpr (I < N) {
        f(std::integral_constant<int, I>{});
        static_for<I + 1, N>(f);
    }
}

// Fold w7 + padded(w5) + padded(w3) + identity into one 7x7 depthwise kernel
// (tap-major [t][c]), bias = b7+b5+b3, AND the cls-token pass-through copy.
__global__ __launch_bounds__(256) void prep_kernel(
    const float* __restrict__ x,
    const float* __restrict__ w7, const float* __restrict__ b7,
    const float* __restrict__ w5, const float* __restrict__ b5,
    const float* __restrict__ w3, const float* __restrict__ b3,
    float* __restrict__ wc, float* __restrict__ bc,
    float* __restrict__ out)
{
    int idx = blockIdx.x * 256 + threadIdx.x;   // 0 .. 33279
    if (idx < DIMC * 49) {
        int c = idx & (DIMC - 1);
        int t = idx >> 9;
        int dy = t / 7, dx = t - dy * 7;
        float v = w7[c * 49 + t];
        if (dy >= 1 && dy <= 5 && dx >= 1 && dx <= 5)
            v += w5[c * 25 + (dy - 1) * 5 + (dx - 1)];
        if (dy >= 2 && dy <= 4 && dx >= 2 && dx <= 4)
            v += w3[c * 9 + (dy - 2) * 3 + (dx - 2)];
        if (dy == 3 && dx == 3) v += 1.0f;      // identity (residual) term
        wc[t * DIMC + c] = v;
    }
    if (idx < DIMC) bc[idx] = b7[idx] + b5[idx] + b3[idx];
    int cidx = idx - DIMC * 49;                 // cls token copy: 16*512 floats
    if (cidx >= 0 && cidx < 16 * DIMC) {
        int b = cidx >> 9, c = cidx & 511;
        size_t off = (size_t)b * NTOK * DIMC + c;
        out[off] = x[off];
    }
}

// Depthwise combined 7x7 conv, channels on lanes.
// R4<->R5 evidence: latency-bound, occupancy-controlled. This version:
//  - ALL spatial addressing is wave-uniform SCALAR: wtile via readfirstlane,
//    pointers = scalar base (b,cg,r,col) + one per-lane `lane` offset ->
//    global_load_dword v, v_laneoff, s[base]; guards are s_cmp/s_cbranch.
//    (R5's 64-bit vector addr math + per-lane cndmask guards were ~2/3 of
//    VALU issue.)
//  - TH=8 via 7-slot static acc ring: vertical halo 2.5x -> 1.75x.
//  - __launch_bounds__(256,8): VGPR capped at 64 -> 8 waves/SIMD. Demand
//    ~54 (ring 28 + row 10 + wr 7 + misc) -> no spill expected.
//    WRITE_SIZE==131072 KB is the spill canary.
__global__ __launch_bounds__(256, 8) void dwconv_kernel(
    const float* __restrict__ x, const float* __restrict__ wc,
    const float* __restrict__ bc, float* __restrict__ out)
{
    __shared__ float wt_lds[49 * 64];              // 12.5 KiB

    const int lane  = threadIdx.x;                 // 0..63 (lane = channel)
    const int wtile = __builtin_amdgcn_readfirstlane((int)threadIdx.y); // 0..3, SGPR
    const int cs    = blockIdx.x;                  // 0..3 col segment (16 cols)
    const int rs    = blockIdx.y & 7;              // row tile (8 rows)
    const int cg    = blockIdx.y >> 3;             // channel group 0..7
    const int b     = blockIdx.z;                  // 0..15
    const int h0    = rs * TH;                     // output row base (SGPR)
    const int w0    = cs * 16 + wtile * WT;        // output col base (SGPR)

    // Stage this channel-group's folded weights: wt_lds[t*64 + c_local]
    for (int j = wtile * 64 + lane; j < 49 * 64; j += 256)
        wt_lds[j] = wc[(j >> 6) * DIMC + (cg << 6) + (j & 63)];
    __syncthreads();

    const float bias = bc[(cg << 6) + lane];
    // Scalar base pointers (everything except the lane offset):
    const float* __restrict__ xb = x   + ((size_t)b * NTOK + 1) * DIMC + (cg << 6);
    float* __restrict__ ob       = out + ((size_t)b * NTOK + 1) * DIMC + (cg << 6);

    float acc[7][WT];     // ring: slot k%7 holds output row h0+k
    float row[WT + 6];    // current input row, cols w0-3 .. w0+WT+2

    static_for<0, TH + 6>([&](auto iC) {
        constexpr int i = decltype(iC)::value;     // input row r = h0-3+i
        const int r = h0 + (i - 3);                // SGPR

        // --- load one input row: scalar base + lane offset, scalar guards ---
        if (r >= 0 && r < GH) {                    // s_cmp + s_cbranch
            const float* __restrict__ rp = xb + (size_t)r * (GW * DIMC);
            static_for<0, WT + 6>([&](auto jC) {
                constexpr int j = decltype(jC)::value;
                const int col = w0 - 3 + j;        // SGPR
                row[j] = (col >= 0 && col < GW) ? rp[col * DIMC + lane] : 0.0f;
            });
        } else {
            static_for<0, WT + 6>([&](auto jC) {
                row[decltype(jC)::value] = 0.0f;
            });
        }

        // --- scatter into the <=7 open output rows: k = i - dy ---
        static_for<0, 7>([&](auto dyC) {
            constexpr int dy = decltype(dyC)::value;
            constexpr int k  = i - dy;
            if constexpr (k >= 0 && k < TH) {
                constexpr int s = k % 7;
                float wr[7];                       // weight row dy (LDS, imm offsets)
                static_for<0, 7>([&](auto dxC) {
                    constexpr int dx = decltype(dxC)::value;
                    wr[dx] = wt_lds[(dy * 7 + dx) * 64 + lane];
                });
                static_for<0, WT>([&](auto tC) {
                    constexpr int t = decltype(tC)::value;
                    float a = (dy == 0) ? bias : acc[s][t];
#pragma unroll
                    for (int dx = 0; dx < 7; ++dx)
                        a = fmaf(wr[dx], row[t + dx], a);
                    acc[s][t] = a;
                });
            }
        });

        // --- output row k = i-6 is complete (before slot reuse at i=k+7) ---
        if constexpr (i >= 6) {
            constexpr int k = i - 6;
            constexpr int s = k % 7;
            static_for<0, WT>([&](auto tC) {
                constexpr int t = decltype(tC)::value;
                ob[((size_t)(h0 + k) * GW + (w0 + t)) * DIMC + lane] = acc[s][t];
            });
        }
    });
}

extern "C" void kernel_launch(void* const* d_in, const int* in_sizes, int n_in,
                              void* d_out, int out_size, void* d_ws, size_t ws_size,
                              hipStream_t stream)
{
    const float* x  = (const float*)d_in[0];
    const float* w7 = (const float*)d_in[1];
    const float* b7 = (const float*)d_in[2];
    const float* w5 = (const float*)d_in[3];
    const float* b5 = (const float*)d_in[4];
    const float* w3 = (const float*)d_in[5];
    const float* b3 = (const float*)d_in[6];
    float* out = (float*)d_out;
    float* wcomb = (float*)d_ws;            // 49*512 floats
    float* bcomb = wcomb + 49 * DIMC;       // 512 floats

    // weights fold + bias + cls copy, one launch (33280 threads)
    prep_kernel<<<130, 256, 0, stream>>>(x, w7, b7, w5, b5, w3, b3,
                                         wcomb, bcomb, out);

    // grid: colseg(4) x (rowtile(8) + 8*cgroup(8)) x batch(16) = 4096 blocks
    dim3 grid(4, 64, 16);
    dim3 block(64, 4, 1);
    dwconv_kernel<<<grid, block, 0, stream>>>(x, wcomb, bcomb, out);
}

// Round 8
// 294.689 us; speedup vs baseline: 4.3433x; 4.3433x over previous
//
#include <hip/hip_runtime.h>
#include <type_traits>

#define DIMC 512
#define NTOK 4097
#define GH 64
#define GW 64
#define TH 4    // output rows per thread (direct acc, no ring)
#define WT 4    // output cols per thread

// Compile-time-for: every array index is a template constant -> SROA promotes.
template <int I, int N, typename F>
__device__ __forceinline__ void static_for(F&& f)
{
    if constexpr (I < N) {
        f(std::integral_constant<int, I>{});
        static_for<I + 1, N>(f);
    }
}

// Fold w7 + padded(w5) + padded(w3) + identity into one 7x7 depthwise kernel
// (tap-major [t][c]), bias = b7+b5+b3, AND the cls-token pass-through copy.
__global__ __launch_bounds__(256) void prep_kernel(
    const float* __restrict__ x,
    const float* __restrict__ w7, const float* __restrict__ b7,
    const float* __restrict__ w5, const float* __restrict__ b5,
    const float* __restrict__ w3, const float* __restrict__ b3,
    float* __restrict__ wc, float* __restrict__ bc,
    float* __restrict__ out)
{
    int idx = blockIdx.x * 256 + threadIdx.x;   // 0 .. 33279
    if (idx < DIMC * 49) {
        int c = idx & (DIMC - 1);
        int t = idx >> 9;
        int dy = t / 7, dx = t - dy * 7;
        float v = w7[c * 49 + t];
        if (dy >= 1 && dy <= 5 && dx >= 1 && dx <= 5)
            v += w5[c * 25 + (dy - 1) * 5 + (dx - 1)];
        if (dy >= 2 && dy <= 4 && dx >= 2 && dx <= 4)
            v += w3[c * 9 + (dy - 2) * 3 + (dx - 2)];
        if (dy == 3 && dx == 3) v += 1.0f;      // identity (residual) term
        wc[t * DIMC + c] = v;
    }
    if (idx < DIMC) bc[idx] = b7[idx] + b5[idx] + b3[idx];
    int cidx = idx - DIMC * 49;                 // cls token copy: 16*512 floats
    if (cidx >= 0 && cidx < 16 * DIMC) {
        int b = cidx >> 9, c = cidx & 511;
        size_t off = (size_t)b * NTOK * DIMC + c;
        out[off] = x[off];
    }
}

// Depthwise combined 7x7 conv, channels on lanes. R4 anchor (127us, VGPR 76,
// zero spill) + two isolated improvements:
//  (1) weight rows as 2x ds_read_b128 from [dy][half][lane][4] layout
//      (lane-contiguous 16B/lane, the standard conflict-free b128 pattern):
//      196 -> 56 ds_read instrs/thread, LDS pipe ~60 -> ~25us.
//  (2) wtile via readfirstlane -> w0/col guards are wave-uniform SGPR values,
//      scalar compares instead of per-lane cndmask chains.
// R6 lesson kept: no launch_bounds cap, no TH=8 ring, default allocator.
__global__ __launch_bounds__(256) void dwconv_kernel(
    const float* __restrict__ x, const float* __restrict__ wc,
    const float* __restrict__ bc, float* __restrict__ out)
{
    __shared__ __align__(16) float wt_lds[7 * 2 * 256];  // 14 KiB

    const int lane  = threadIdx.x;                 // 0..63 (lane = channel)
    const int wtile = __builtin_amdgcn_readfirstlane((int)threadIdx.y); // SGPR 0..3
    const int cs    = blockIdx.x;                  // 0..3 col segment (16 cols)
    const int rs    = blockIdx.y & 15;             // row tile (4 rows)
    const int cg    = blockIdx.y >> 4;             // channel group 0..7
    const int b     = blockIdx.z;                  // 0..15
    const int cc    = (cg << 6) + lane;            // channel 0..511
    const int h0    = rs * TH;                     // output row base
    const int w0    = cs * 16 + wtile * WT;        // output col base (SGPR)

    // Stage folded weights: chunk dy*2+h holds taps dy*7 + h*4 + q (q=0..3),
    // laid out [chunk][lane][q]; tap 7 of each row is zero padding.
    for (int idx = wtile * 64 + lane; idx < 7 * 2 * 256; idx += 256) {
        int chunk = idx >> 8, within = idx & 255;
        int l = within >> 2, q = within & 3;
        int dy = chunk >> 1, tap = (chunk & 1) * 4 + q;
        wt_lds[idx] = (tap < 7) ? wc[(dy * 7 + tap) * DIMC + (cg << 6) + l] : 0.0f;
    }
    __syncthreads();

    const float bias = bc[cc];
    const float* __restrict__ xin = x   + ((size_t)b * NTOK + 1) * DIMC + cc;
    float* __restrict__ op        = out + ((size_t)b * NTOK + 1) * DIMC + cc;

    float acc[TH][WT];

    static_for<0, TH + 6>([&](auto iC) {
        constexpr int i = decltype(iC)::value;     // input row r = h0-3+i
        const int r = h0 + (i - 3);

        // --- load one input row (10 coalesced 256B/wave loads, scalar guards) ---
        float row[WT + 6];
        if (r >= 0 && r < GH) {                    // wave-uniform guard
            const float* __restrict__ rp = xin + (size_t)r * (GW * DIMC);
            static_for<0, WT + 6>([&](auto jC) {
                constexpr int j = decltype(jC)::value;
                const int col = w0 - 3 + j;        // SGPR: guard is scalar
                row[j] = (col >= 0 && col < GW) ? rp[(size_t)col * DIMC] : 0.0f;
            });
        } else {
            static_for<0, WT + 6>([&](auto jC) {
                row[decltype(jC)::value] = 0.0f;
            });
        }

        // --- scatter into the <=TH open output rows: k = i - dy ---
        static_for<0, 7>([&](auto dyC) {
            constexpr int dy = decltype(dyC)::value;
            constexpr int k  = i - dy;
            if constexpr (k >= 0 && k < TH) {
                const float4 wa = *reinterpret_cast<const float4*>(
                    &wt_lds[(dy * 2 + 0) * 256 + (lane << 2)]);
                const float4 wb = *reinterpret_cast<const float4*>(
                    &wt_lds[(dy * 2 + 1) * 256 + (lane << 2)]);
                static_for<0, WT>([&](auto tC) {
                    constexpr int t = decltype(tC)::value;
                    float a = (dy == 0) ? bias : acc[k][t];
                    a = fmaf(wa.x, row[t + 0], a);
                    a = fmaf(wa.y, row[t + 1], a);
                    a = fmaf(wa.z, row[t + 2], a);
                    a = fmaf(wa.w, row[t + 3], a);
                    a = fmaf(wb.x, row[t + 4], a);
                    a = fmaf(wb.y, row[t + 5], a);
                    a = fmaf(wb.z, row[t + 6], a);
                    acc[k][t] = a;
                });
            }
        });

        // --- output row k = i-6 is complete ---
        if constexpr (i >= 6) {
            constexpr int k = i - 6;
            static_for<0, WT>([&](auto tC) {
                constexpr int t = decltype(tC)::value;
                op[((size_t)(h0 + k) * GW + (w0 + t)) * DIMC] = acc[k][t];
            });
        }
    });
}

extern "C" void kernel_launch(void* const* d_in, const int* in_sizes, int n_in,
                              void* d_out, int out_size, void* d_ws, size_t ws_size,
                              hipStream_t stream)
{
    const float* x  = (const float*)d_in[0];
    const float* w7 = (const float*)d_in[1];
    const float* b7 = (const float*)d_in[2];
    const float* w5 = (const float*)d_in[3];
    const float* b5 = (const float*)d_in[4];
    const float* w3 = (const float*)d_in[5];
    const float* b3 = (const float*)d_in[6];
    float* out = (float*)d_out;
    float* wcomb = (float*)d_ws;            // 49*512 floats
    float* bcomb = wcomb + 49 * DIMC;       // 512 floats

    // weights fold + bias + cls copy, one launch (33280 threads)
    prep_kernel<<<130, 256, 0, stream>>>(x, w7, b7, w5, b5, w3, b3,
                                         wcomb, bcomb, out);

    // grid: colseg(4) x (rowtile(16) + 16*cgroup(8)) x batch(16) = 8192 blocks
    dim3 grid(4, 128, 16);
    dim3 block(64, 4, 1);
    dwconv_kernel<<<grid, block, 0, stream>>>(x, wcomb, bcomb, out);
}